// Round 3
// 687.970 us; speedup vs baseline: 1.0230x; 1.0230x over previous
//
#include <hip/hip_runtime.h>
#include <math.h>

#define C 64
#define K 20
#define MT 256        // points per pass1 block (8 waves x 32 rows)
#define ASTR 72       // B LDS row stride (bf16 units): frag b128 reads 2-way = free
#define LGSTR 22      // logit LDS stride (bf16)

// fallback (recompute) path constants
#define P1_TPB 128
#define P1_ROWS 128
#define LSTR 65

typedef __attribute__((ext_vector_type(8))) short bf16x8;
typedef __attribute__((ext_vector_type(4))) float f32x4;

// ---------------- helpers ----------------

__device__ __forceinline__ float wave_reduce_add(float v) {
#pragma unroll
  for (int m = 32; m > 0; m >>= 1) v += __shfl_xor(v, m, 64);
  return v;
}

__device__ __forceinline__ unsigned short f2bf16(float x) {
  union { float f; unsigned u; } v; v.f = x;
  unsigned r = v.u + 0x7FFFu + ((v.u >> 16) & 1u);   // RTNE
  return (unsigned short)(r >> 16);
}

__device__ __forceinline__ float bf16lo(unsigned u) { return __uint_as_float(u << 16); }
__device__ __forceinline__ float bf16hi(unsigned u) { return __uint_as_float(u & 0xFFFF0000u); }

__device__ __forceinline__ bf16x8 cvt8(float4 lo, float4 hi) {
  bf16x8 r;
  r[0] = (short)f2bf16(lo.x); r[1] = (short)f2bf16(lo.y);
  r[2] = (short)f2bf16(lo.z); r[3] = (short)f2bf16(lo.w);
  r[4] = (short)f2bf16(hi.x); r[5] = (short)f2bf16(hi.y);
  r[6] = (short)f2bf16(hi.z); r[7] = (short)f2bf16(hi.w);
  return r;
}

__device__ __forceinline__ void point_losses(long long p, float bp0, float bp1, float bp2,
                                             const float* __restrict__ coord,
                                             const int* __restrict__ instance,
                                             const float* __restrict__ centroid,
                                             float& l1m, float& cosm, float& m) {
  float cx = coord[p * 3 + 0], cy = coord[p * 3 + 1], cz = coord[p * 3 + 2];
  float gx = centroid[p * 3 + 0] - cx;
  float gy = centroid[p * 3 + 1] - cy;
  float gz = centroid[p * 3 + 2] - cz;
  m = (instance[p] != -1) ? 1.0f : 0.0f;
  float l1 = fabsf(bp0 - gx) + fabsf(bp1 - gy) + fabsf(bp2 - gz);
  float npn = sqrtf(bp0 * bp0 + bp1 * bp1 + bp2 * bp2) + 1e-8f;
  float ngn = sqrtf(gx * gx + gy * gy + gz * gz) + 1e-8f;
  float cs = -(bp0 * gx + bp1 * gy + bp2 * gz) / (npn * ngn);
  l1m = l1 * m;
  cosm = cs * m;
}

// acc layout (floats): [0]=sum w*nll [1]=sum w [2]=sum l1*m [3]=sum cos*m [4]=sum m
// [8..71]=sum_h  [72..135]=sum_h2  [136..199]=BN scale  [200..263]=BN shift

// ---------------- pass 1: MFMA dual-GEMM + BN stats + CE + fragment-layout bf16 spill ----
// A-fragments loaded direct global->reg (no LDS staging, no staging barrier).
// h spilled register->global in fragment-native layout (coalesced dwordx2), consumed by
// pass2_frag with the same mapping.
// b1 is dropped: BatchNorm(train) output is invariant to a constant channel shift.

__global__ __launch_bounds__(512, 4)
void pass1_kernel(const float* __restrict__ feat,
                  const int* __restrict__ segment,
                  const float* __restrict__ W1,
                  const float* __restrict__ Wseg,
                  const float* __restrict__ bseg,
                  const float* __restrict__ cw,
                  float* __restrict__ acc,
                  unsigned short* __restrict__ hout,
                  int store_h, int n) {
  __shared__ __align__(16) unsigned short Bs[96 * ASTR];    // 13824 B: W1^T rows 0..63, Wseg^T rows 64..95
  __shared__ __align__(16) unsigned short lgL[256 * LGSTR]; // 11264 B: bf16 logits
  __shared__ float cs1[8 * 64];
  __shared__ float cs2[8 * 64];
  __shared__ float wpart[8];

  const int t = threadIdx.x;
  const int wv = t >> 6;          // 0..7
  const int L = t & 63;
  const int colL = L & 15;
  const int quad = L >> 4;
  const long long base = (long long)blockIdx.x * MT;
  const int rbase = wv * 32;

  // issue all feat fragment loads up-front (8x dwordx4 per lane, independent)
  float4 af[2][2][2];   // [rt][kh][half]
  {
    const float* frow = feat + (base + rbase + colL) * C + quad * 8;
#pragma unroll
    for (int rt = 0; rt < 2; ++rt)
#pragma unroll
      for (int kh = 0; kh < 2; ++kh) {
        const float* p = frow + rt * (16 * C) + kh * 32;
        af[rt][kh][0] = *(const float4*)p;
        af[rt][kh][1] = *(const float4*)(p + 4);
      }
  }

  // stage W1^T (rows = out channel j, cols = k) -- once per block, L2-hot
#pragma unroll
  for (int i = 0; i < 8; ++i) {
    int e = t + i * 512;                       // e = k*64 + j
    Bs[(e & 63) * ASTR + (e >> 6)] = f2bf16(W1[e]);
  }
  // stage Wseg^T padded to 32 output cols (pad rows zero)
#pragma unroll
  for (int i = 0; i < 4; ++i) {
    int e = t + i * 512;                       // e over 64x32
    int k = e >> 5, j = e & 31;
    float v = (j < K) ? Wseg[k * K + j] : 0.0f;
    Bs[(64 + j) * ASTR + k] = f2bf16(v);
  }

  // convert feat frags to bf16 (waitcnt on loads folds in here, overlapped w/ barrier)
  bf16x8 a[2][2];
#pragma unroll
  for (int rt = 0; rt < 2; ++rt)
#pragma unroll
    for (int kh = 0; kh < 2; ++kh)
      a[rt][kh] = cvt8(af[rt][kh][0], af[rt][kh][1]);
  __syncthreads();   // Bs ready

  // MFMA: wave wv computes rows [wv*32, wv*32+32), col tiles 0..3 = h, 4..5 = logits
  f32x4 accr[2][6];
#pragma unroll
  for (int rt = 0; rt < 2; ++rt)
#pragma unroll
    for (int ct = 0; ct < 6; ++ct) accr[rt][ct] = (f32x4){0.f, 0.f, 0.f, 0.f};

#pragma unroll
  for (int kh = 0; kh < 2; ++kh) {
    const int k0 = kh * 32 + quad * 8;
    bf16x8 b[6];
#pragma unroll
    for (int ct = 0; ct < 6; ++ct)
      b[ct] = *(const bf16x8*)(Bs + (ct * 16 + colL) * ASTR + k0);
#pragma unroll
    for (int rt = 0; rt < 2; ++rt)
#pragma unroll
      for (int ct = 0; ct < 6; ++ct)
        accr[rt][ct] = __builtin_amdgcn_mfma_f32_16x16x32_bf16(a[rt][kh], b[ct], accr[rt][ct], 0, 0, 0);
  }

  // C-layout (col=lane&15, row=quad*4+reg):
  //   - h -> global spill in fragment layout (no LDS round trip, no barrier dep)
  //   - logits -> small LDS for CE
  //   - BN stats from registers
  float s1[4] = {0, 0, 0, 0}, s2[4] = {0, 0, 0, 0};
#pragma unroll
  for (int rt = 0; rt < 2; ++rt) {
    const int row0 = rbase + rt * 16 + quad * 4;
#pragma unroll
    for (int ct = 0; ct < 4; ++ct) {
      ushort4 o;
      float v0 = accr[rt][ct][0], v1 = accr[rt][ct][1];
      float v2 = accr[rt][ct][2], v3 = accr[rt][ct][3];
      s1[ct] += v0 + v1 + v2 + v3;
      s2[ct] = __builtin_fmaf(v0, v0, s2[ct]);
      s2[ct] = __builtin_fmaf(v1, v1, s2[ct]);
      s2[ct] = __builtin_fmaf(v2, v2, s2[ct]);
      s2[ct] = __builtin_fmaf(v3, v3, s2[ct]);
      o.x = f2bf16(v0); o.y = f2bf16(v1); o.z = f2bf16(v2); o.w = f2bf16(v3);
      if (store_h)
        *(ushort4*)(hout + base * C + wv * 2048 + (rt * 4 + ct) * 256 + L * 4) = o;
    }
#pragma unroll
    for (int r = 0; r < 4; ++r) {
      lgL[(row0 + r) * LGSTR + colL] = f2bf16(accr[rt][4][r]);
      if (colL < K - 16) lgL[(row0 + r) * LGSTR + 16 + colL] = f2bf16(accr[rt][5][r]);
    }
  }
#pragma unroll
  for (int ct = 0; ct < 4; ++ct) {
    float a1 = s1[ct]; a1 += __shfl_xor(a1, 16, 64); a1 += __shfl_xor(a1, 32, 64);
    float a2 = s2[ct]; a2 += __shfl_xor(a2, 16, 64); a2 += __shfl_xor(a2, 32, 64);
    if (L < 16) { cs1[wv * 64 + ct * 16 + colL] = a1; cs2[wv * 64 + ct * 16 + colL] = a2; }
  }
  __syncthreads();

  // CE per-thread from LDS logits (waves 0-3, row t)
  if (t < 256) {
    float lg[K];
    const unsigned* lrow = (const unsigned*)lgL + t * (LGSTR / 2);
#pragma unroll
    for (int u = 0; u < K / 2; ++u) {
      unsigned q = lrow[u];
      lg[2 * u]     = bf16lo(q) + bseg[2 * u];
      lg[2 * u + 1] = bf16hi(q) + bseg[2 * u + 1];
    }
    const int seg = segment[base + t];
    const bool valid = (seg != -1);
    const int tgt = valid ? seg : 0;
    float mx = lg[0], lt = lg[0];
#pragma unroll
    for (int c = 1; c < K; ++c) { mx = fmaxf(mx, lg[c]); lt = (c == tgt) ? lg[c] : lt; }
    float se = 0.f;
#pragma unroll
    for (int c = 0; c < K; ++c) se += __expf(lg[c] - mx);
    float nll = mx + __logf(se) - lt;
    float w = valid ? cw[tgt] : 0.f;
    float rwn = wave_reduce_add(w * nll);
    float rw = wave_reduce_add(w);
    if (L == 0) { wpart[wv * 2] = rwn; wpart[wv * 2 + 1] = rw; }
  }
  __syncthreads();

  if (t == 0) {
    atomicAdd(&acc[0], wpart[0] + wpart[2] + wpart[4] + wpart[6]);
    atomicAdd(&acc[1], wpart[1] + wpart[3] + wpart[5] + wpart[7]);
  }
  if (t < C) {
    float u1 = 0.f, u2 = 0.f;
#pragma unroll
    for (int w8 = 0; w8 < 8; ++w8) { u1 += cs1[w8 * 64 + t]; u2 += cs2[w8 * 64 + t]; }
    atomicAdd(&acc[8 + t], u1);
    atomicAdd(&acc[72 + t], u2);
  }
}

// ---------------- prep: fold BN stats into scale/shift once ----------------

__global__ void prep_kernel(const float* __restrict__ gamma,
                            const float* __restrict__ beta,
                            float* __restrict__ acc, int n) {
  int j = threadIdx.x;
  float inv_n = 1.0f / (float)n;
  float mean = acc[8 + j] * inv_n;
  float var = fmaxf(acc[72 + j] * inv_n - mean * mean, 0.0f);
  float sc = gamma[j] * rsqrtf(var + 1e-3f);
  acc[136 + j] = sc;
  acc[200 + j] = beta[j] - mean * sc;
}

// ---------------- pass 2: fragment-layout consume, BN+ReLU+GEMV + losses ----------------
// No LDS staging: coalesced 8 B/lane reads; 64-wide GEMV done as in-lane partials over
// 4 cols then 4-step shfl_xor butterfly over the 16-lane colL group.

__global__ __launch_bounds__(256)
void pass2_frag(const unsigned short* __restrict__ hsrc,
                const float* __restrict__ coord,
                const int* __restrict__ instance,
                const float* __restrict__ centroid,
                const float* __restrict__ W2,
                const float* __restrict__ b2,
                float* __restrict__ acc, int n) {
  __shared__ float part[4][3];
  const int t = threadIdx.x;
  const int w = t >> 6, L = t & 63;
  const int colL = L & 15, quad = L >> 4;
  const long long base = (long long)blockIdx.x * MT;

  float scv[4], shv[4], w20[4], w21[4], w22[4];
#pragma unroll
  for (int ct = 0; ct < 4; ++ct) {
    int j = ct * 16 + colL;
    scv[ct] = acc[136 + j];
    shv[ct] = acc[200 + j];
    w20[ct] = W2[j * 3 + 0];
    w21[ct] = W2[j * 3 + 1];
    w22[ct] = W2[j * 3 + 2];
  }
  const float bb0 = b2[0], bb1 = b2[1], bb2 = b2[2];

  float l1a = 0.f, cosa = 0.f, ma = 0.f;
#pragma unroll
  for (int g = 0; g < 2; ++g) {
    const int wv8 = 2 * w + g;     // pass1 wave whose chunk we consume
    const ushort4* src = (const ushort4*)(hsrc + base * C + wv8 * 2048);
#pragma unroll
    for (int rt = 0; rt < 2; ++rt) {
      float d[12];
#pragma unroll
      for (int e = 0; e < 12; ++e) d[e] = 0.f;
#pragma unroll
      for (int ct = 0; ct < 4; ++ct) {
        ushort4 q = src[(rt * 4 + ct) * 64 + L];
        unsigned short qa[4] = { q.x, q.y, q.z, q.w };
#pragma unroll
        for (int r = 0; r < 4; ++r) {
          float v = __uint_as_float((unsigned)qa[r] << 16);
          float y = fmaxf(__builtin_fmaf(v, scv[ct], shv[ct]), 0.0f);
          d[r * 3 + 0] = __builtin_fmaf(y, w20[ct], d[r * 3 + 0]);
          d[r * 3 + 1] = __builtin_fmaf(y, w21[ct], d[r * 3 + 1]);
          d[r * 3 + 2] = __builtin_fmaf(y, w22[ct], d[r * 3 + 2]);
        }
      }
#pragma unroll
      for (int m = 1; m <= 8; m <<= 1)
#pragma unroll
        for (int e = 0; e < 12; ++e) d[e] += __shfl_xor(d[e], m, 64);
      if (colL < 4) {
        const int r = colL;
        float bp0 = d[r * 3 + 0] + bb0;
        float bp1 = d[r * 3 + 1] + bb1;
        float bp2 = d[r * 3 + 2] + bb2;
        const long long p = base + wv8 * 32 + rt * 16 + quad * 4 + r;
        float l1m, cosm, mm;
        point_losses(p, bp0, bp1, bp2, coord, instance, centroid, l1m, cosm, mm);
        l1a += l1m; cosa += cosm; ma += mm;
      }
    }
  }
  float r0 = wave_reduce_add(l1a);
  float r1 = wave_reduce_add(cosa);
  float r2 = wave_reduce_add(ma);
  if (L == 0) { part[w][0] = r0; part[w][1] = r1; part[w][2] = r2; }
  __syncthreads();
  if (t == 0) {
    float a0 = 0, a1 = 0, a2 = 0;
#pragma unroll
    for (int k = 0; k < 4; ++k) { a0 += part[k][0]; a1 += part[k][1]; a2 += part[k][2]; }
    atomicAdd(&acc[2], a0);
    atomicAdd(&acc[3], a1);
    atomicAdd(&acc[4], a2);
  }
}

// ---------------- pass 2 fallback: recompute h from feat (no spill space) ----------------

__global__ __launch_bounds__(P1_TPB, 2)
void pass2_recompute(const float* __restrict__ feat,
                     const float* __restrict__ coord,
                     const int* __restrict__ instance,
                     const float* __restrict__ centroid,
                     const float* __restrict__ W1,
                     const float* __restrict__ W2,
                     const float* __restrict__ b2,
                     float* __restrict__ acc, int n) {
  __shared__ float lds[P1_ROWS * LSTR];
  __shared__ float part[2][3];
  const int tid = threadIdx.x;
  const int wave = tid >> 6;
  const int lane = tid & 63;
  const long long base = (long long)blockIdx.x * P1_ROWS;

  {
    const float4* src = (const float4*)(feat + base * C);
#pragma unroll
    for (int i = 0; i < 16; ++i) {
      int g = tid + i * P1_TPB;
      float4 v = src[g];
      float* d = &lds[(g >> 4) * LSTR + ((g & 15) << 2)];
      d[0] = v.x; d[1] = v.y; d[2] = v.z; d[3] = v.w;
    }
  }
  __syncthreads();

  float h[C];
#pragma unroll
  for (int j = 0; j < C; ++j) h[j] = 0.0f;   // b1 dropped (BN shift-invariant)
  const float* frow = &lds[tid * LSTR];
#pragma unroll 4
  for (int k = 0; k < C; ++k) {
    float fk = frow[k];
#pragma unroll
    for (int j = 0; j < C; ++j) h[j] = __builtin_fmaf(fk, W1[k * C + j], h[j]);
  }

  const float* ssc = acc + 136;
  const float* ssh = acc + 200;
  float bp0 = b2[0], bp1 = b2[1], bp2 = b2[2];
#pragma unroll
  for (int j = 0; j < C; ++j) {
    float y = fmaxf(__builtin_fmaf(h[j], ssc[j], ssh[j]), 0.0f);
    bp0 = __builtin_fmaf(y, W2[j * 3 + 0], bp0);
    bp1 = __builtin_fmaf(y, W2[j * 3 + 1], bp1);
    bp2 = __builtin_fmaf(y, W2[j * 3 + 2], bp2);
  }

  const long long p = base + tid;
  float l1m, cosm, m;
  point_losses(p, bp0, bp1, bp2, coord, instance, centroid, l1m, cosm, m);
  float r0 = wave_reduce_add(l1m);
  float r1 = wave_reduce_add(cosm);
  float r2 = wave_reduce_add(m);
  if (lane == 0) { part[wave][0] = r0; part[wave][1] = r1; part[wave][2] = r2; }
  __syncthreads();
  if (tid == 0) {
    atomicAdd(&acc[2], part[0][0] + part[1][0]);
    atomicAdd(&acc[3], part[0][1] + part[1][1]);
    atomicAdd(&acc[4], part[0][2] + part[1][2]);
  }
}

// ---------------- finalize ----------------

__global__ void finalize_kernel(const float* __restrict__ acc, float* __restrict__ out) {
  if (threadIdx.x == 0 && blockIdx.x == 0) {
    float seg = acc[0] / acc[1];
    float den = acc[4] + 1e-8f;
    float l1 = acc[2] / den;
    float cs = acc[3] / den;
    out[0] = seg + l1 + cs;
    out[1] = seg;
    out[2] = l1;
    out[3] = cs;
  }
}

// ---------------- launch ----------------

extern "C" void kernel_launch(void* const* d_in, const int* in_sizes, int n_in,
                              void* d_out, int out_size, void* d_ws, size_t ws_size,
                              hipStream_t stream) {
  const float* feat = (const float*)d_in[0];
  const float* coord = (const float*)d_in[1];
  const int* segment = (const int*)d_in[2];
  const int* instance = (const int*)d_in[3];
  const float* centroid = (const float*)d_in[4];
  const float* W1 = (const float*)d_in[5];
  // d_in[6] = b1 : unused (BN train-mode output is invariant to channel shift)
  const float* gamma = (const float*)d_in[7];
  const float* beta = (const float*)d_in[8];
  const float* W2 = (const float*)d_in[9];
  const float* b2 = (const float*)d_in[10];
  const float* Wseg = (const float*)d_in[11];
  const float* bseg = (const float*)d_in[12];
  const float* cw = (const float*)d_in[13];

  const int n = in_sizes[0] / C;  // 1048576

  float* acc = (float*)d_ws;
  unsigned short* hbuf = (unsigned short*)((char*)d_ws + 2048);
  const size_t need = 2048 + (size_t)n * C * sizeof(unsigned short);
  const int store_h = (ws_size >= need) ? 1 : 0;

  size_t zbytes = ws_size < 2048 ? ws_size : 2048;
  hipMemsetAsync(d_ws, 0, zbytes, stream);

  pass1_kernel<<<n / MT, 512, 0, stream>>>(feat, segment, W1, Wseg, bseg, cw,
                                           acc, hbuf, store_h, n);
  prep_kernel<<<1, 64, 0, stream>>>(gamma, beta, acc, n);
  if (store_h) {
    pass2_frag<<<n / MT, 256, 0, stream>>>(hbuf, coord, instance, centroid,
                                           W2, b2, acc, n);
  } else {
    pass2_recompute<<<n / P1_ROWS, P1_TPB, 0, stream>>>(feat, coord, instance, centroid,
                                                        W1, W2, b2, acc, n);
  }
  finalize_kernel<<<1, 1, 0, stream>>>(acc, (float*)d_out);
}

// Round 4
// 564.122 us; speedup vs baseline: 1.2475x; 1.2195x over previous
//
#include <hip/hip_runtime.h>
#include <math.h>

#define C 64
#define K 20
#define TPB 256            // 4 waves
#define ROWS_PER_TILE 128  // 4 waves x 32 rows
#define NT 8               // tiles per block -> 1024 points/block
#define ASTR 72            // Bs LDS row stride (bf16): b128 reads 2-way = free

// atomic buckets
#define NB 8
#define BSTR 512                 // floats per bucket
#define SCOFF (NB * BSTR)        // scale at ws[SCOFF..+63], shift at ws[SCOFF+64..+127]
#define HOFF 18432               // hbuf byte offset in ws

// fallback (recompute) path constants
#define P1_TPB 128
#define P1_ROWS 128
#define LSTR 65

typedef __attribute__((ext_vector_type(8))) short bf16x8;
typedef __attribute__((ext_vector_type(4))) float f32x4;

// ---------------- helpers ----------------

__device__ __forceinline__ float wave_reduce_add(float v) {
#pragma unroll
  for (int m = 32; m > 0; m >>= 1) v += __shfl_xor(v, m, 64);
  return v;
}

__device__ __forceinline__ unsigned short f2bf16(float x) {
  union { float f; unsigned u; } v; v.f = x;
  unsigned r = v.u + 0x7FFFu + ((v.u >> 16) & 1u);   // RTNE
  return (unsigned short)(r >> 16);
}

__device__ __forceinline__ bf16x8 cvt8(float4 lo, float4 hi) {
  bf16x8 r;
  r[0] = (short)f2bf16(lo.x); r[1] = (short)f2bf16(lo.y);
  r[2] = (short)f2bf16(lo.z); r[3] = (short)f2bf16(lo.w);
  r[4] = (short)f2bf16(hi.x); r[5] = (short)f2bf16(hi.y);
  r[6] = (short)f2bf16(hi.z); r[7] = (short)f2bf16(hi.w);
  return r;
}

// bucket layout (floats): [0]=sum w*nll [1]=sum w [2]=sum l1*m [3]=sum cos*m [4]=sum m
// [8..71]=sum_h  [72..135]=sum_h2 ; global: ws[SCOFF..]=BN scale, ws[SCOFF+64..]=BN shift

// ---------------- pass 1: pipelined MFMA dual-GEMM + reg-CE + frag-layout spill --------
// NT tiles per block; tile i+1 feat loads issued before tile i epilogue; zero barriers in
// the loop (CE fully in registers via 16-lane butterflies). b1 dropped (BN shift-invar).

__global__ __launch_bounds__(TPB, 4)
void pass1_kernel(const float* __restrict__ feat,
                  const int* __restrict__ segment,
                  const float* __restrict__ W1,
                  const float* __restrict__ Wseg,
                  const float* __restrict__ bseg,
                  const float* __restrict__ cw,
                  float* __restrict__ ws,
                  unsigned short* __restrict__ hout,
                  int store_h, int n) {
  __shared__ __align__(16) unsigned short Bs[96 * ASTR];  // W1^T rows 0..63, Wseg^T 64..95
  __shared__ float cred[512];                             // [2][4 waves][64 ch]
  __shared__ float wpart[8];

  const int t = threadIdx.x;
  const int wv = t >> 6;          // 0..3
  const int L = t & 63;
  const int colL = L & 15;
  const int quad = L >> 4;
  const long long blockbase = (long long)blockIdx.x * (ROWS_PER_TILE * NT);
  const int rbase = wv * 32;

  float* bucket = ws + (blockIdx.x & (NB - 1)) * BSTR;

  // persistent per-lane accumulators (across tiles)
  float s1[4] = {0, 0, 0, 0}, s2[4] = {0, 0, 0, 0};
  float wnll = 0.f, wsum = 0.f;

  const float bsega = bseg[colL];
  const float bsegb = (colL < 4) ? bseg[16 + colL] : 0.f;

  float4 af[8];   // prefetched feat fragments [rt*4 + kh*2 + half]
  auto issue_tile = [&](int it) {
    const long long trow = blockbase + (long long)it * ROWS_PER_TILE + rbase;
    const float* frow = feat + (trow + colL) * C + quad * 8;
#pragma unroll
    for (int rt = 0; rt < 2; ++rt)
#pragma unroll
      for (int kh = 0; kh < 2; ++kh) {
        const float* p = frow + rt * (16 * C) + kh * 32;
        af[rt * 4 + kh * 2 + 0] = *(const float4*)p;
        af[rt * 4 + kh * 2 + 1] = *(const float4*)(p + 4);
      }
  };

  issue_tile(0);

  // stage W1^T (rows = out channel j, cols = k); covers tile-0 load latency
#pragma unroll
  for (int i = 0; i < 16; ++i) {
    int e = t + i * 256;                       // e = k*64 + j
    Bs[(e & 63) * ASTR + (e >> 6)] = f2bf16(W1[e]);
  }
  // stage Wseg^T padded to 32 output cols
#pragma unroll
  for (int i = 0; i < 8; ++i) {
    int e = t + i * 256;                       // over 64x32
    int k = e >> 5, j = e & 31;
    float v = (j < K) ? Wseg[k * K + j] : 0.0f;
    Bs[(64 + j) * ASTR + k] = f2bf16(v);
  }
  __syncthreads();   // Bs ready; never written again

  for (int it = 0; it < NT; ++it) {
    // segment rows for CURRENT tile: issue early, consumed in phase D
    int segc[8];
    {
      const long long trow = blockbase + (long long)it * ROWS_PER_TILE + rbase;
#pragma unroll
      for (int rt = 0; rt < 2; ++rt)
#pragma unroll
        for (int r = 0; r < 4; ++r)
          segc[rt * 4 + r] = segment[trow + rt * 16 + quad * 4 + r];
    }

    // consume prefetched feat (vmcnt wait folds here), then issue next tile
    bf16x8 a[2][2];
#pragma unroll
    for (int rt = 0; rt < 2; ++rt)
#pragma unroll
      for (int kh = 0; kh < 2; ++kh)
        a[rt][kh] = cvt8(af[rt * 4 + kh * 2], af[rt * 4 + kh * 2 + 1]);
    if (it + 1 < NT) issue_tile(it + 1);

    // ---- phase A: h columns (ct 0..3) ----
    f32x4 ah[2][4];
#pragma unroll
    for (int rt = 0; rt < 2; ++rt)
#pragma unroll
      for (int ct = 0; ct < 4; ++ct) ah[rt][ct] = (f32x4){0.f, 0.f, 0.f, 0.f};
#pragma unroll
    for (int kh = 0; kh < 2; ++kh) {
      const int k0 = kh * 32 + quad * 8;
#pragma unroll
      for (int ct = 0; ct < 4; ++ct) {
        bf16x8 b = *(const bf16x8*)(Bs + (ct * 16 + colL) * ASTR + k0);
        ah[0][ct] = __builtin_amdgcn_mfma_f32_16x16x32_bf16(a[0][kh], b, ah[0][ct], 0, 0, 0);
        ah[1][ct] = __builtin_amdgcn_mfma_f32_16x16x32_bf16(a[1][kh], b, ah[1][ct], 0, 0, 0);
      }
    }

    // ---- phase B: spill (frag layout, fire-and-forget) + BN stats ----
    {
      unsigned short* uso = hout + (long long)(blockIdx.x * NT + it) * 8192 + wv * 2048;
#pragma unroll
      for (int rt = 0; rt < 2; ++rt)
#pragma unroll
        for (int ct = 0; ct < 4; ++ct) {
          float v0 = ah[rt][ct][0], v1 = ah[rt][ct][1];
          float v2 = ah[rt][ct][2], v3 = ah[rt][ct][3];
          s1[ct] += v0 + v1 + v2 + v3;
          s2[ct] = __builtin_fmaf(v0, v0, s2[ct]);
          s2[ct] = __builtin_fmaf(v1, v1, s2[ct]);
          s2[ct] = __builtin_fmaf(v2, v2, s2[ct]);
          s2[ct] = __builtin_fmaf(v3, v3, s2[ct]);
          if (store_h) {
            ushort4 o;
            o.x = f2bf16(v0); o.y = f2bf16(v1); o.z = f2bf16(v2); o.w = f2bf16(v3);
            *(ushort4*)(uso + (rt * 4 + ct) * 256 + L * 4) = o;
          }
        }
    }

    // ---- phase C: logit columns (ct 4..5) ----
    f32x4 alg[2][2];
#pragma unroll
    for (int rt = 0; rt < 2; ++rt)
#pragma unroll
      for (int cc = 0; cc < 2; ++cc) alg[rt][cc] = (f32x4){0.f, 0.f, 0.f, 0.f};
#pragma unroll
    for (int kh = 0; kh < 2; ++kh) {
      const int k0 = kh * 32 + quad * 8;
#pragma unroll
      for (int cc = 0; cc < 2; ++cc) {
        bf16x8 b = *(const bf16x8*)(Bs + ((4 + cc) * 16 + colL) * ASTR + k0);
        alg[0][cc] = __builtin_amdgcn_mfma_f32_16x16x32_bf16(a[0][kh], b, alg[0][cc], 0, 0, 0);
        alg[1][cc] = __builtin_amdgcn_mfma_f32_16x16x32_bf16(a[1][kh], b, alg[1][cc], 0, 0, 0);
      }
    }

    // ---- phase D: CE fully in registers (16-lane butterflies, no LDS/barrier) ----
#pragma unroll
    for (int rt = 0; rt < 2; ++rt)
#pragma unroll
      for (int r = 0; r < 4; ++r) {
        float la = alg[rt][0][r] + bsega;                                   // col = colL
        float lb = (colL < 4) ? alg[rt][1][r] + bsegb : -3.0e38f;           // col = 16+colL
        const int sg = segc[rt * 4 + r];
        const bool valid = (sg != -1);
        const int tgt = valid ? sg : 0;
        float mx = fmaxf(la, lb);
        mx = fmaxf(mx, __shfl_xor(mx, 1, 64));
        mx = fmaxf(mx, __shfl_xor(mx, 2, 64));
        mx = fmaxf(mx, __shfl_xor(mx, 4, 64));
        mx = fmaxf(mx, __shfl_xor(mx, 8, 64));
        float e = __expf(la - mx) + ((colL < 4) ? __expf(lb - mx) : 0.f);
        float tp = ((colL == tgt) ? la : 0.f) + ((colL + 16 == tgt) ? lb : 0.f);
#pragma unroll
        for (int m = 1; m <= 8; m <<= 1) {
          e += __shfl_xor(e, m, 64);
          tp += __shfl_xor(tp, m, 64);
        }
        float nll = mx + __logf(e) - tp;
        float wct = cw[tgt];
        if (colL == 0) {
          float w = valid ? wct : 0.f;
          wnll += w * nll;
          wsum += w;
        }
      }
  }

  // ---- block-end reduction (amortized over NT tiles) ----
#pragma unroll
  for (int ct = 0; ct < 4; ++ct) {
    float a1 = s1[ct]; a1 += __shfl_xor(a1, 16, 64); a1 += __shfl_xor(a1, 32, 64);
    float a2 = s2[ct]; a2 += __shfl_xor(a2, 16, 64); a2 += __shfl_xor(a2, 32, 64);
    if (L < 16) { cred[wv * 64 + ct * 16 + colL] = a1; cred[256 + wv * 64 + ct * 16 + colL] = a2; }
  }
  {
    float rwn = wave_reduce_add(wnll);
    float rw = wave_reduce_add(wsum);
    if (L == 0) { wpart[wv * 2] = rwn; wpart[wv * 2 + 1] = rw; }
  }
  __syncthreads();
  if (t == 0) {
    atomicAdd(&bucket[0], wpart[0] + wpart[2] + wpart[4] + wpart[6]);
    atomicAdd(&bucket[1], wpart[1] + wpart[3] + wpart[5] + wpart[7]);
  }
  if (t < C) {
    float u1 = cred[t] + cred[64 + t] + cred[128 + t] + cred[192 + t];
    float u2 = cred[256 + t] + cred[320 + t] + cred[384 + t] + cred[448 + t];
    atomicAdd(&bucket[8 + t], u1);
    atomicAdd(&bucket[72 + t], u2);
  }
}

// ---------------- prep: fold BN stats into scale/shift once ----------------

__global__ void prep_kernel(const float* __restrict__ gamma,
                            const float* __restrict__ beta,
                            float* __restrict__ ws, int n) {
  int j = threadIdx.x;
  float s1 = 0.f, s2 = 0.f;
#pragma unroll
  for (int b = 0; b < NB; ++b) { s1 += ws[b * BSTR + 8 + j]; s2 += ws[b * BSTR + 72 + j]; }
  float inv_n = 1.0f / (float)n;
  float mean = s1 * inv_n;
  float var = fmaxf(s2 * inv_n - mean * mean, 0.0f);
  float sc = gamma[j] * rsqrtf(var + 1e-3f);
  ws[SCOFF + j] = sc;
  ws[SCOFF + 64 + j] = beta[j] - mean * sc;
}

// ---------------- pass 2: pipelined frag-layout consume, BN+ReLU+GEMV + losses --------

__global__ __launch_bounds__(TPB, 4)
void pass2_frag(const unsigned short* __restrict__ hsrc,
                const float* __restrict__ coord,
                const int* __restrict__ instance,
                const float* __restrict__ centroid,
                const float* __restrict__ W2,
                const float* __restrict__ b2,
                float* __restrict__ ws, int n) {
  __shared__ float part[4][3];
  const int t = threadIdx.x;
  const int w = t >> 6, L = t & 63;
  const int colL = L & 15, quad = L >> 4;
  float* bucket = ws + (blockIdx.x & (NB - 1)) * BSTR;

  const float* ssc = ws + SCOFF;
  const float* ssh = ws + SCOFF + 64;
  float scv[4], shv[4], w20[4], w21[4], w22[4];
#pragma unroll
  for (int ct = 0; ct < 4; ++ct) {
    int j = ct * 16 + colL;
    scv[ct] = ssc[j];
    shv[ct] = ssh[j];
    w20[ct] = W2[j * 3 + 0];
    w21[ct] = W2[j * 3 + 1];
    w22[ct] = W2[j * 3 + 2];
  }
  const float bb0 = b2[0], bb1 = b2[1], bb2 = b2[2];

  float l1a = 0.f, cosa = 0.f, ma = 0.f;

  ushort4 hv[8];
  auto issue_h = [&](int it) {
    const ushort4* src = (const ushort4*)(hsrc + (long long)(blockIdx.x * NT + it) * 8192 + w * 2048);
#pragma unroll
    for (int s = 0; s < 8; ++s) hv[s] = src[s * 64 + L];
  };
  float pc[2][3], pg[2][3]; int pin[2];
  auto issue_pts = [&](int it) {
    if (colL < 4) {
      const long long rowb = (long long)blockIdx.x * (ROWS_PER_TILE * NT) +
                             (long long)it * ROWS_PER_TILE + w * 32 + quad * 4 + colL;
#pragma unroll
      for (int rt = 0; rt < 2; ++rt) {
        long long p = rowb + rt * 16;
        pc[rt][0] = coord[p * 3 + 0]; pc[rt][1] = coord[p * 3 + 1]; pc[rt][2] = coord[p * 3 + 2];
        pg[rt][0] = centroid[p * 3 + 0]; pg[rt][1] = centroid[p * 3 + 1]; pg[rt][2] = centroid[p * 3 + 2];
        pin[rt] = instance[p];
      }
    }
  };

  issue_h(0);
  issue_pts(0);

  for (int it = 0; it < NT; ++it) {
    ushort4 hc[8];
#pragma unroll
    for (int s = 0; s < 8; ++s) hc[s] = hv[s];
    if (it + 1 < NT) issue_h(it + 1);

#pragma unroll
    for (int rt = 0; rt < 2; ++rt) {
      float d[12];
#pragma unroll
      for (int e = 0; e < 12; ++e) d[e] = 0.f;
#pragma unroll
      for (int ct = 0; ct < 4; ++ct) {
        ushort4 q = hc[rt * 4 + ct];
        unsigned short qa[4] = { q.x, q.y, q.z, q.w };
#pragma unroll
        for (int r = 0; r < 4; ++r) {
          float v = __uint_as_float((unsigned)qa[r] << 16);
          float y = fmaxf(__builtin_fmaf(v, scv[ct], shv[ct]), 0.0f);
          d[r * 3 + 0] = __builtin_fmaf(y, w20[ct], d[r * 3 + 0]);
          d[r * 3 + 1] = __builtin_fmaf(y, w21[ct], d[r * 3 + 1]);
          d[r * 3 + 2] = __builtin_fmaf(y, w22[ct], d[r * 3 + 2]);
        }
      }
#pragma unroll
      for (int m = 1; m <= 8; m <<= 1)
#pragma unroll
        for (int e = 0; e < 12; ++e) d[e] += __shfl_xor(d[e], m, 64);
      if (colL < 4) {
        const int r = colL;
        float bp0 = d[r * 3 + 0] + bb0;
        float bp1 = d[r * 3 + 1] + bb1;
        float bp2 = d[r * 3 + 2] + bb2;
        float gx = pg[rt][0] - pc[rt][0];
        float gy = pg[rt][1] - pc[rt][1];
        float gz = pg[rt][2] - pc[rt][2];
        float m = (pin[rt] != -1) ? 1.0f : 0.0f;
        float l1 = fabsf(bp0 - gx) + fabsf(bp1 - gy) + fabsf(bp2 - gz);
        float npn = sqrtf(bp0 * bp0 + bp1 * bp1 + bp2 * bp2) + 1e-8f;
        float ngn = sqrtf(gx * gx + gy * gy + gz * gz) + 1e-8f;
        float cs = -(bp0 * gx + bp1 * gy + bp2 * gz) / (npn * ngn);
        l1a += l1 * m;
        cosa += cs * m;
        ma += m;
      }
    }
    if (it + 1 < NT) issue_pts(it + 1);
  }

  float r0 = wave_reduce_add(l1a);
  float r1 = wave_reduce_add(cosa);
  float r2 = wave_reduce_add(ma);
  if (L == 0) { part[w][0] = r0; part[w][1] = r1; part[w][2] = r2; }
  __syncthreads();
  if (t == 0) {
    float a0 = 0, a1 = 0, a2 = 0;
#pragma unroll
    for (int k = 0; k < 4; ++k) { a0 += part[k][0]; a1 += part[k][1]; a2 += part[k][2]; }
    atomicAdd(&bucket[2], a0);
    atomicAdd(&bucket[3], a1);
    atomicAdd(&bucket[4], a2);
  }
}

// ---------------- pass 2 fallback: recompute h from feat (no spill space) ----------------

__global__ __launch_bounds__(P1_TPB, 2)
void pass2_recompute(const float* __restrict__ feat,
                     const float* __restrict__ coord,
                     const int* __restrict__ instance,
                     const float* __restrict__ centroid,
                     const float* __restrict__ W1,
                     const float* __restrict__ W2,
                     const float* __restrict__ b2,
                     float* __restrict__ ws, int n) {
  __shared__ float lds[P1_ROWS * LSTR];
  __shared__ float part[2][3];
  const int tid = threadIdx.x;
  const int wave = tid >> 6;
  const int lane = tid & 63;
  const long long base = (long long)blockIdx.x * P1_ROWS;
  float* bucket = ws + (blockIdx.x & (NB - 1)) * BSTR;

  {
    const float4* src = (const float4*)(feat + base * C);
#pragma unroll
    for (int i = 0; i < 16; ++i) {
      int g = tid + i * P1_TPB;
      float4 v = src[g];
      float* d = &lds[(g >> 4) * LSTR + ((g & 15) << 2)];
      d[0] = v.x; d[1] = v.y; d[2] = v.z; d[3] = v.w;
    }
  }
  __syncthreads();

  float h[C];
#pragma unroll
  for (int j = 0; j < C; ++j) h[j] = 0.0f;   // b1 dropped (BN shift-invariant)
  const float* frow = &lds[tid * LSTR];
#pragma unroll 4
  for (int k = 0; k < C; ++k) {
    float fk = frow[k];
#pragma unroll
    for (int j = 0; j < C; ++j) h[j] = __builtin_fmaf(fk, W1[k * C + j], h[j]);
  }

  const float* ssc = ws + SCOFF;
  const float* ssh = ws + SCOFF + 64;
  float bp0 = b2[0], bp1 = b2[1], bp2 = b2[2];
#pragma unroll
  for (int j = 0; j < C; ++j) {
    float y = fmaxf(__builtin_fmaf(h[j], ssc[j], ssh[j]), 0.0f);
    bp0 = __builtin_fmaf(y, W2[j * 3 + 0], bp0);
    bp1 = __builtin_fmaf(y, W2[j * 3 + 1], bp1);
    bp2 = __builtin_fmaf(y, W2[j * 3 + 2], bp2);
  }

  const long long p = base + tid;
  float cx = coord[p * 3 + 0], cy = coord[p * 3 + 1], cz = coord[p * 3 + 2];
  float gx = centroid[p * 3 + 0] - cx;
  float gy = centroid[p * 3 + 1] - cy;
  float gz = centroid[p * 3 + 2] - cz;
  float m = (instance[p] != -1) ? 1.0f : 0.0f;
  float l1 = fabsf(bp0 - gx) + fabsf(bp1 - gy) + fabsf(bp2 - gz);
  float npn = sqrtf(bp0 * bp0 + bp1 * bp1 + bp2 * bp2) + 1e-8f;
  float ngn = sqrtf(gx * gx + gy * gy + gz * gz) + 1e-8f;
  float cs = -(bp0 * gx + bp1 * gy + bp2 * gz) / (npn * ngn);
  float r0 = wave_reduce_add(l1 * m);
  float r1 = wave_reduce_add(cs * m);
  float r2 = wave_reduce_add(m);
  if (lane == 0) { part[wave][0] = r0; part[wave][1] = r1; part[wave][2] = r2; }
  __syncthreads();
  if (tid == 0) {
    atomicAdd(&bucket[2], part[0][0] + part[1][0]);
    atomicAdd(&bucket[3], part[0][1] + part[1][1]);
    atomicAdd(&bucket[4], part[0][2] + part[1][2]);
  }
}

// ---------------- finalize ----------------

__global__ void finalize_kernel(const float* __restrict__ ws, float* __restrict__ out) {
  if (threadIdx.x == 0 && blockIdx.x == 0) {
    float a0 = 0, a1 = 0, a2 = 0, a3 = 0, a4 = 0;
#pragma unroll
    for (int b = 0; b < NB; ++b) {
      const float* bk = ws + b * BSTR;
      a0 += bk[0]; a1 += bk[1]; a2 += bk[2]; a3 += bk[3]; a4 += bk[4];
    }
    float seg = a0 / a1;
    float den = a4 + 1e-8f;
    float l1 = a2 / den;
    float cs = a3 / den;
    out[0] = seg + l1 + cs;
    out[1] = seg;
    out[2] = l1;
    out[3] = cs;
  }
}

// ---------------- launch ----------------

extern "C" void kernel_launch(void* const* d_in, const int* in_sizes, int n_in,
                              void* d_out, int out_size, void* d_ws, size_t ws_size,
                              hipStream_t stream) {
  const float* feat = (const float*)d_in[0];
  const float* coord = (const float*)d_in[1];
  const int* segment = (const int*)d_in[2];
  const int* instance = (const int*)d_in[3];
  const float* centroid = (const float*)d_in[4];
  const float* W1 = (const float*)d_in[5];
  // d_in[6] = b1 : unused (BN train-mode output is invariant to channel shift)
  const float* gamma = (const float*)d_in[7];
  const float* beta = (const float*)d_in[8];
  const float* W2 = (const float*)d_in[9];
  const float* b2 = (const float*)d_in[10];
  const float* Wseg = (const float*)d_in[11];
  const float* bseg = (const float*)d_in[12];
  const float* cw = (const float*)d_in[13];

  const int n = in_sizes[0] / C;  // 1048576

  float* ws = (float*)d_ws;
  unsigned short* hbuf = (unsigned short*)((char*)d_ws + HOFF);
  const size_t need = (size_t)HOFF + (size_t)n * C * sizeof(unsigned short);
  const int store_h = (ws_size >= need) ? 1 : 0;

  size_t zbytes = ws_size < (size_t)(NB * BSTR * 4) ? ws_size : (size_t)(NB * BSTR * 4);
  hipMemsetAsync(d_ws, 0, zbytes, stream);

  const int nblk = n / (ROWS_PER_TILE * NT);   // 1024
  pass1_kernel<<<nblk, TPB, 0, stream>>>(feat, segment, W1, Wseg, bseg, cw,
                                         ws, hbuf, store_h, n);
  prep_kernel<<<1, 64, 0, stream>>>(gamma, beta, ws, n);
  if (store_h) {
    pass2_frag<<<nblk, TPB, 0, stream>>>(hbuf, coord, instance, centroid,
                                         W2, b2, ws, n);
  } else {
    pass2_recompute<<<n / P1_ROWS, P1_TPB, 0, stream>>>(feat, coord, instance, centroid,
                                                        W1, W2, b2, ws, n);
  }
  finalize_kernel<<<1, 1, 0, stream>>>(ws, (float*)d_out);
}